// Round 5
// baseline (278.979 us; speedup 1.0000x reference)
//
#include <hip/hip_runtime.h>
#include <math.h>

#ifndef M_PI
#define M_PI 3.14159265358979323846
#endif

#define NAANG 1152
#define NDET  736
#define NPIX  512
#define PADN  2048
#define NHALF 1025   // PADN/2 + 1

// ---- workspace layout (byte offsets) ----
// double FILT[1025]            @ 0        (8200 B, pad 8320)
// float  h[2048]               @ 8320     (8192 B)   [pi/(2NA) scale folded]
// float4 trig[1152]            @ 16512    (18432 B)  (cb, sb, K*cb, K*sb)
// float  filtered[1152*736]    @ 34944    (3391488 B)
// float  partial[NCH*512*512]  @ 3426432  (NCH MiB)
#define OFF_FILTD 0
#define OFF_H     8320
#define OFF_TRIG  16512
#define OFF_FS    34944
#define OFF_PART  3426432

// ---------------------------------------------------------------------------
// Kernel 1: FILT[m] = Shepp-Logan half-spectrum (double precision).
// ---------------------------------------------------------------------------
__global__ void filt_spec_kernel(double* __restrict__ filt_d) {
    __shared__ double red[256];
    const int m = blockIdx.x;          // 0..1024
    const int t = threadIdx.x;
    double s = 0.0;
    for (int j = t; j < 1024; j += 256) {
        int n = (j < 512) ? (2 * j + 1) : (2047 - 2 * j);
        double fj = -1.0 / ((M_PI * n) * (M_PI * n));
        double ang = (2.0 * M_PI) * (double)m * (double)(2 * j + 1) / (double)PADN;
        s += fj * cos(ang);
    }
    red[t] = s;
    __syncthreads();
    for (int w = 128; w > 0; w >>= 1) {
        if (t < w) red[t] += red[t + w];
        __syncthreads();
    }
    if (t == 0) {
        double four = 2.0 * (0.25 + red[0]);
        if (m > 0) {
            double om = M_PI * (double)m / (double)PADN;
            four *= sin(om) / om;
        }
        filt_d[m] = four;
    }
}

// ---------------------------------------------------------------------------
// Kernel 2: h[k] = irfft(FILT,2048)[k] * pi/(2*NA); blocks k<1152 also fill
// the trig table on lane 0 (fused to save a launch).
// ---------------------------------------------------------------------------
__global__ void h_kernel(const double* __restrict__ filt_d, float* __restrict__ h,
                         float4* __restrict__ trig) {
    __shared__ double red[256];
    const int k = blockIdx.x;          // 0..2047
    const int t = threadIdx.x;
    if (t == 0 && k < NAANG) {
        double ang = 2.0 * M_PI * (double)k / (double)NAANG + M_PI / 2.0;
        double c = cos(ang), s = sin(ang);
        double K = 1085.6 / 1.2858;    // DSD/DU (vox scaling cancels)
        trig[k] = make_float4((float)c, (float)s, (float)(K * c), (float)(K * s));
    }
    double s = 0.0;
    for (int m = t; m <= 1024; m += 256) {
        double c;
        if (m == 0) c = 1.0;
        else if (m == 1024) c = (k & 1) ? -1.0 : 1.0;
        else c = 2.0 * cos((2.0 * M_PI) * (double)m * (double)k / (double)PADN);
        s += filt_d[m] * c;
    }
    red[t] = s;
    __syncthreads();
    for (int w = 128; w > 0; w >>= 1) {
        if (t < w) red[t] += red[t + w];
        __syncthreads();
    }
    if (t == 0)
        h[k] = (float)(red[0] / (double)PADN * (M_PI / (2.0 * (double)NAANG)));
}

// ---------------------------------------------------------------------------
// Kernel 3: circular convolution, aligned-b128 form (unchanged from R3).
// ---------------------------------------------------------------------------
__global__ void conv_kernel(const float* __restrict__ x,
                            const float* __restrict__ h,
                            float* __restrict__ fs) {
    __shared__ float sh2[2816];        // h duplicated: sh2[i] = h[i & 2047]
    __shared__ float srow[NDET];
    const int row = blockIdx.x;
    const int t = threadIdx.x;
    const float4* h4 = (const float4*)h;
    for (int i = t; i < 704; i += 192) ((float4*)sh2)[i] = h4[i & 511];
    const float4* x4 = (const float4*)(x + row * NDET);
    for (int i = t; i < NDET / 4; i += 192) ((float4*)srow)[i] = x4[i];
    __syncthreads();

    const int t4 = 4 * t;
    float o0 = 0.f, o1 = 0.f, o2 = 0.f, o3 = 0.f;
    #pragma unroll 2
    for (int j = 0; j < NDET; j += 4) {
        float4 r4 = *(const float4*)&srow[j];
        const int A = t4 + PADN - j;
        float4 hlo = *(const float4*)&sh2[A - 4];
        float4 hhi = *(const float4*)&sh2[A];
        o0 = fmaf(r4.x, hhi.x, o0); o0 = fmaf(r4.y, hlo.w, o0);
        o0 = fmaf(r4.z, hlo.z, o0); o0 = fmaf(r4.w, hlo.y, o0);
        o1 = fmaf(r4.x, hhi.y, o1); o1 = fmaf(r4.y, hhi.x, o1);
        o1 = fmaf(r4.z, hlo.w, o1); o1 = fmaf(r4.w, hlo.z, o1);
        o2 = fmaf(r4.x, hhi.z, o2); o2 = fmaf(r4.y, hhi.y, o2);
        o2 = fmaf(r4.z, hhi.x, o2); o2 = fmaf(r4.w, hlo.w, o2);
        o3 = fmaf(r4.x, hhi.w, o3); o3 = fmaf(r4.y, hhi.z, o3);
        o3 = fmaf(r4.z, hhi.y, o3); o3 = fmaf(r4.w, hhi.x, o3);
    }
    if (t < NDET / 4)
        *(float4*)&fs[row * NDET + t4] = make_float4(o0, o1, o2, o3);
}

// ---------------------------------------------------------------------------
// Kernel 4: fan-beam backprojection with LDS row staging.
// Per angle: row (736 floats = 184 float4s) staged into a double-buffered LDS
// slot via coalesced float4 loads. Block = 256 threads = 4 waves; wave w
// stages float4s [46w, 46w+46) using lanes 0..45 (4*46 = 184 exactly).
// Gathers hit LDS (ds_read2_b32) instead of L1 — removes the ~107 µs TD/L1
// gather floor. One barrier per angle: writing rows[(a+1)&1] BEFORE the
// end-of-iter barrier is safe (its last readers synced at end of iter a-1).
// 2 pixels/thread (adjacent y): den1=den0-sb, kpe1=kpe0+K*cb.
// grid (2, 256, NCH) -> NCH=8: 2048 blocks = 8/CU * 4 waves = 32 waves/CU.
// ---------------------------------------------------------------------------
template<int NCH>
__global__ __launch_bounds__(256, 8)
void backproj_kernel(const float* __restrict__ fs,
                     const float4* __restrict__ trig,
                     float* __restrict__ partial) {
    constexpr int ACL = NAANG / NCH;
    __shared__ float4 st[ACL];
    __shared__ float rows[2][NDET];
    const int t = threadIdx.x;
    const int abase = blockIdx.z * ACL;
    for (int i = t; i < ACL; i += 256) st[i] = trig[abase + i];

    // staging assignment: wave w handles float4s [46w, 46w+46), lanes 0..45
    const int sidx = (t >> 6) * 46 + (t & 63);   // 0..183 for active lanes
    const bool sact = (t & 63) < 46;
    if (sact) ((float4*)rows[0])[sidx] = ((const float4*)(fs + abase * NDET))[sidx];
    __syncthreads();

    const int ix = blockIdx.x * 256 + t;
    const int iy = blockIdx.y * 2;
    const float xs  = (float)ix - 255.5f;
    const float ys0 = (float)iy - 255.5f;
    const float Dg = 850.0f;                  // 595/0.7 exactly

    float acc0 = 0.f, acc1 = 0.f;
    for (int a = 0; a < ACL; ++a) {
        float4 pf;
        const bool dopf = sact && (a + 1 < ACL);
        if (dopf) pf = ((const float4*)(fs + (abase + a + 1) * NDET))[sidx];

        const float* row = rows[a & 1];
        float4 q = st[a];                     // cb, sb, K*cb, K*sb
        float den0 = fmaf(-xs, q.x, fmaf(-ys0, q.y, Dg));
        float kpe0 = fmaf(ys0, q.z, -(xs * q.w));
        float den1 = den0 - q.y;
        float kpe1 = kpe0 + q.z;
        float r0 = __builtin_amdgcn_rcpf(den0);
        float r1 = __builtin_amdgcn_rcpf(den1);
        float iu0 = fmaf(kpe0, r0, 367.5f);   // (ND-1)/2
        float iu1 = fmaf(kpe1, r1, 367.5f);
        float f0 = floorf(iu0), f1 = floorf(iu1);
        int   i0 = (int)f0,     i1 = (int)f1;
        int   c0 = min(max(i0, 0), NDET - 2);
        int   c1 = min(max(i1, 0), NDET - 2);
        float fr0 = iu0 - f0,   fr1 = iu1 - f1;
        float a0 = row[c0], b0 = row[c0 + 1];
        float a1 = row[c1], b1 = row[c1 + 1];
        float v0 = fmaf(fr0, b0 - a0, a0);
        float v1 = fmaf(fr1, b1 - a1, a1);
        float d0 = Dg * r0, d1 = Dg * r1;
        float w0 = d0 * d0, w1 = d1 * d1;
        w0 = ((unsigned)i0 < (unsigned)(NDET - 1)) ? w0 : 0.f;
        w1 = ((unsigned)i1 < (unsigned)(NDET - 1)) ? w1 : 0.f;
        acc0 = fmaf(w0, v0, acc0);
        acc1 = fmaf(w1, v1, acc1);

        if (dopf) ((float4*)rows[(a + 1) & 1])[sidx] = pf;
        __syncthreads();
    }
    partial[(blockIdx.z * NPIX + iy) * NPIX + ix] = acc0;
    partial[(blockIdx.z * NPIX + iy + 1) * NPIX + ix] = acc1;
}

// ---------------------------------------------------------------------------
// Kernel 5: sum partials + HU window.
// ---------------------------------------------------------------------------
template<int NCH>
__global__ void combine_kernel(const float* __restrict__ partial,
                               float* __restrict__ out) {
    int p = blockIdx.x * 256 + threadIdx.x;
    float s = 0.f;
    #pragma unroll
    for (int c = 0; c < NCH; ++c) s += partial[c * NPIX * NPIX + p];
    // (1000*((fbp-0.0192)/0.0192)+1024)/4096 = fbp*(1000/0.0192/4096) + 24/4096
    out[p] = fmaf(s, (float)(1000.0 / 0.0192 / 4096.0), 0.005859375f);
}

extern "C" void kernel_launch(void* const* d_in, const int* in_sizes, int n_in,
                              void* d_out, int out_size, void* d_ws, size_t ws_size,
                              hipStream_t stream) {
    const float* x = (const float*)d_in[0];     // (1,1,1152,736) fp32 sinogram
    float* out = (float*)d_out;                 // (1,1,512,512) fp32

    char* ws = (char*)d_ws;
    double* filt_d = (double*)(ws + OFF_FILTD);
    float*  h      = (float*)(ws + OFF_H);
    float4* trig   = (float4*)(ws + OFF_TRIG);
    float*  fs     = (float*)(ws + OFF_FS);
    float*  part   = (float*)(ws + OFF_PART);

    filt_spec_kernel<<<NHALF, 256, 0, stream>>>(filt_d);
    h_kernel<<<PADN, 256, 0, stream>>>(filt_d, h, trig);
    conv_kernel<<<NAANG, 192, 0, stream>>>(x, h, fs);

    const size_t pbytes = (size_t)NPIX * NPIX * 4;
    if (ws_size >= OFF_PART + 8 * pbytes) {
        backproj_kernel<8><<<dim3(2, 256, 8), 256, 0, stream>>>(fs, trig, part);
        combine_kernel<8><<<NPIX * NPIX / 256, 256, 0, stream>>>(part, out);
    } else if (ws_size >= OFF_PART + 4 * pbytes) {
        backproj_kernel<4><<<dim3(2, 256, 4), 256, 0, stream>>>(fs, trig, part);
        combine_kernel<4><<<NPIX * NPIX / 256, 256, 0, stream>>>(part, out);
    } else if (ws_size >= OFF_PART + 2 * pbytes) {
        backproj_kernel<2><<<dim3(2, 256, 2), 256, 0, stream>>>(fs, trig, part);
        combine_kernel<2><<<NPIX * NPIX / 256, 256, 0, stream>>>(part, out);
    } else {
        backproj_kernel<1><<<dim3(2, 256, 1), 256, 0, stream>>>(fs, trig, part);
        combine_kernel<1><<<NPIX * NPIX / 256, 256, 0, stream>>>(part, out);
    }
}

// Round 6
// 265.102 us; speedup vs baseline: 1.0523x; 1.0523x over previous
//
#include <hip/hip_runtime.h>
#include <math.h>

#ifndef M_PI
#define M_PI 3.14159265358979323846
#endif

#define NAANG 1152
#define NDET  736
#define NPIX  512
#define PADN  2048
#define NHALF 1025   // PADN/2 + 1

// ---- workspace layout (byte offsets) ----
// double FILT[1025]            @ 0        (8200 B, pad 8320)
// float  h[2048]               @ 8320     (8192 B)   [pi/(2NA) scale folded]
// float4 trig[1152]            @ 16512    (18432 B)  (cb, sb, K*cb, K*sb)
// float  filtered[1152*736]    @ 34944    (3391488 B)
// float  partial[NCH*512*512]  @ 3426432  (NCH MiB)
#define OFF_FILTD 0
#define OFF_H     8320
#define OFF_TRIG  16512
#define OFF_FS    34944
#define OFF_PART  3426432

typedef float f32x2 __attribute__((ext_vector_type(2)));

// 8-byte gather of row[c], row[c+1]; address only 4B-aligned — let the
// compiler pick dwordx2-unaligned (gfx9+ supports it) or split; both correct.
static __device__ __forceinline__ f32x2 load2(const float* p) {
    f32x2 r;
    __builtin_memcpy(&r, p, 8);
    return r;
}

// ---------------------------------------------------------------------------
// Kernel 1: FILT[m] = Shepp-Logan half-spectrum (double precision).
// ---------------------------------------------------------------------------
__global__ void filt_spec_kernel(double* __restrict__ filt_d) {
    __shared__ double red[256];
    const int m = blockIdx.x;          // 0..1024
    const int t = threadIdx.x;
    double s = 0.0;
    for (int j = t; j < 1024; j += 256) {
        int n = (j < 512) ? (2 * j + 1) : (2047 - 2 * j);
        double fj = -1.0 / ((M_PI * n) * (M_PI * n));
        double ang = (2.0 * M_PI) * (double)m * (double)(2 * j + 1) / (double)PADN;
        s += fj * cos(ang);
    }
    red[t] = s;
    __syncthreads();
    for (int w = 128; w > 0; w >>= 1) {
        if (t < w) red[t] += red[t + w];
        __syncthreads();
    }
    if (t == 0) {
        double four = 2.0 * (0.25 + red[0]);
        if (m > 0) {
            double om = M_PI * (double)m / (double)PADN;
            four *= sin(om) / om;
        }
        filt_d[m] = four;
    }
}

// ---------------------------------------------------------------------------
// Kernel 2: h[k] = irfft(FILT,2048)[k] * pi/(2*NA); blocks k<1152 also fill
// the trig table on lane 0 (fused to save a launch).
// ---------------------------------------------------------------------------
__global__ void h_kernel(const double* __restrict__ filt_d, float* __restrict__ h,
                         float4* __restrict__ trig) {
    __shared__ double red[256];
    const int k = blockIdx.x;          // 0..2047
    const int t = threadIdx.x;
    if (t == 0 && k < NAANG) {
        double ang = 2.0 * M_PI * (double)k / (double)NAANG + M_PI / 2.0;
        double c = cos(ang), s = sin(ang);
        double K = 1085.6 / 1.2858;    // DSD/DU (vox scaling cancels)
        trig[k] = make_float4((float)c, (float)s, (float)(K * c), (float)(K * s));
    }
    double s = 0.0;
    for (int m = t; m <= 1024; m += 256) {
        double c;
        if (m == 0) c = 1.0;
        else if (m == 1024) c = (k & 1) ? -1.0 : 1.0;
        else c = 2.0 * cos((2.0 * M_PI) * (double)m * (double)k / (double)PADN);
        s += filt_d[m] * c;
    }
    red[t] = s;
    __syncthreads();
    for (int w = 128; w > 0; w >>= 1) {
        if (t < w) red[t] += red[t + w];
        __syncthreads();
    }
    if (t == 0)
        h[k] = (float)(red[0] / (double)PADN * (M_PI / (2.0 * (double)NAANG)));
}

// ---------------------------------------------------------------------------
// Kernel 3: circular convolution, aligned-b128 form (unchanged).
// ---------------------------------------------------------------------------
__global__ void conv_kernel(const float* __restrict__ x,
                            const float* __restrict__ h,
                            float* __restrict__ fs) {
    __shared__ float sh2[2816];        // h duplicated: sh2[i] = h[i & 2047]
    __shared__ float srow[NDET];
    const int row = blockIdx.x;
    const int t = threadIdx.x;
    const float4* h4 = (const float4*)h;
    for (int i = t; i < 704; i += 192) ((float4*)sh2)[i] = h4[i & 511];
    const float4* x4 = (const float4*)(x + row * NDET);
    for (int i = t; i < NDET / 4; i += 192) ((float4*)srow)[i] = x4[i];
    __syncthreads();

    const int t4 = 4 * t;
    float o0 = 0.f, o1 = 0.f, o2 = 0.f, o3 = 0.f;
    #pragma unroll 2
    for (int j = 0; j < NDET; j += 4) {
        float4 r4 = *(const float4*)&srow[j];
        const int A = t4 + PADN - j;
        float4 hlo = *(const float4*)&sh2[A - 4];
        float4 hhi = *(const float4*)&sh2[A];
        o0 = fmaf(r4.x, hhi.x, o0); o0 = fmaf(r4.y, hlo.w, o0);
        o0 = fmaf(r4.z, hlo.z, o0); o0 = fmaf(r4.w, hlo.y, o0);
        o1 = fmaf(r4.x, hhi.y, o1); o1 = fmaf(r4.y, hhi.x, o1);
        o1 = fmaf(r4.z, hlo.w, o1); o1 = fmaf(r4.w, hlo.z, o1);
        o2 = fmaf(r4.x, hhi.z, o2); o2 = fmaf(r4.y, hhi.y, o2);
        o2 = fmaf(r4.z, hhi.x, o2); o2 = fmaf(r4.w, hlo.w, o2);
        o3 = fmaf(r4.x, hhi.w, o3); o3 = fmaf(r4.y, hhi.z, o3);
        o3 = fmaf(r4.z, hhi.y, o3); o3 = fmaf(r4.w, hhi.x, o3);
    }
    if (t < NDET / 4)
        *(float4*)&fs[row * NDET + t4] = make_float4(o0, o1, o2, o3);
}

// ---------------------------------------------------------------------------
// Kernel 4: fan-beam backprojection, barrier-free, 4 pixels/thread (y-column).
// Pixels k=1..3 derive geometry incrementally: den_k = den0 - k*sb,
// kpe_k = kpe0 + k*K*cb (2 adds each). Four independent gather chains per
// thread hide L1 latency; gathers are single 8B loads (row[c], row[c+1]).
// grid (2, 128, NCH); NCH=8 -> 2048 blocks = 8/CU * 4 waves = 32 waves/CU.
// ---------------------------------------------------------------------------
template<int NCH>
__global__ __launch_bounds__(256, 8)
void backproj_kernel(const float* __restrict__ fs,
                     const float4* __restrict__ trig,
                     float* __restrict__ partial) {
    constexpr int ACL = NAANG / NCH;
    __shared__ float4 st[ACL];
    const int t = threadIdx.x;
    const int abase = blockIdx.z * ACL;
    for (int i = t; i < ACL; i += 256) st[i] = trig[abase + i];
    __syncthreads();

    const int ix = blockIdx.x * 256 + t;
    const int iy = blockIdx.y * 4;
    const float xs  = (float)ix - 255.5f;
    const float ys0 = (float)iy - 255.5f;
    const float Dg = 850.0f;                  // 595/0.7 exactly

    const float* rowp = fs + (size_t)abase * NDET;
    float acc0 = 0.f, acc1 = 0.f, acc2 = 0.f, acc3 = 0.f;
    for (int a = 0; a < ACL; ++a, rowp += NDET) {
        float4 q = st[a];                     // cb, sb, K*cb, K*sb
        float sb2 = q.y + q.y;
        float kc2 = q.z + q.z;
        float den0 = fmaf(-xs, q.x, fmaf(-ys0, q.y, Dg));
        float kpe0 = fmaf(ys0, q.z, -(xs * q.w));
        float den1 = den0 - q.y, den2 = den0 - sb2, den3 = den2 - q.y;
        float kpe1 = kpe0 + q.z, kpe2 = kpe0 + kc2, kpe3 = kpe2 + q.z;

        float r0 = __builtin_amdgcn_rcpf(den0);
        float r1 = __builtin_amdgcn_rcpf(den1);
        float r2 = __builtin_amdgcn_rcpf(den2);
        float r3 = __builtin_amdgcn_rcpf(den3);
        float iu0 = fmaf(kpe0, r0, 367.5f);
        float iu1 = fmaf(kpe1, r1, 367.5f);
        float iu2 = fmaf(kpe2, r2, 367.5f);
        float iu3 = fmaf(kpe3, r3, 367.5f);
        float f0 = floorf(iu0), f1 = floorf(iu1), f2 = floorf(iu2), f3 = floorf(iu3);
        int   i0 = (int)f0, i1 = (int)f1, i2 = (int)f2, i3 = (int)f3;
        int   c0 = min(max(i0, 0), NDET - 2);   // v_med3_i32
        int   c1 = min(max(i1, 0), NDET - 2);
        int   c2 = min(max(i2, 0), NDET - 2);
        int   c3 = min(max(i3, 0), NDET - 2);
        // issue all four 8B gathers before consuming any
        f32x2 g0 = load2(rowp + c0);
        f32x2 g1 = load2(rowp + c1);
        f32x2 g2 = load2(rowp + c2);
        f32x2 g3 = load2(rowp + c3);
        float fr0 = iu0 - f0, fr1 = iu1 - f1, fr2 = iu2 - f2, fr3 = iu3 - f3;
        float v0 = fmaf(fr0, g0.y - g0.x, g0.x);
        float v1 = fmaf(fr1, g1.y - g1.x, g1.x);
        float v2 = fmaf(fr2, g2.y - g2.x, g2.x);
        float v3 = fmaf(fr3, g3.y - g3.x, g3.x);
        float d0 = Dg * r0, d1 = Dg * r1, d2 = Dg * r2, d3 = Dg * r3;
        float w0 = d0 * d0, w1 = d1 * d1, w2 = d2 * d2, w3 = d3 * d3;
        w0 = ((unsigned)i0 < (unsigned)(NDET - 1)) ? w0 : 0.f;
        w1 = ((unsigned)i1 < (unsigned)(NDET - 1)) ? w1 : 0.f;
        w2 = ((unsigned)i2 < (unsigned)(NDET - 1)) ? w2 : 0.f;
        w3 = ((unsigned)i3 < (unsigned)(NDET - 1)) ? w3 : 0.f;
        acc0 = fmaf(w0, v0, acc0);
        acc1 = fmaf(w1, v1, acc1);
        acc2 = fmaf(w2, v2, acc2);
        acc3 = fmaf(w3, v3, acc3);
    }
    float* outp = partial + ((size_t)blockIdx.z * NPIX + iy) * NPIX + ix;
    outp[0 * NPIX] = acc0;
    outp[1 * NPIX] = acc1;
    outp[2 * NPIX] = acc2;
    outp[3 * NPIX] = acc3;
}

// ---------------------------------------------------------------------------
// Kernel 5: sum partials + HU window.
// ---------------------------------------------------------------------------
template<int NCH>
__global__ void combine_kernel(const float* __restrict__ partial,
                               float* __restrict__ out) {
    int p = blockIdx.x * 256 + threadIdx.x;
    float s = 0.f;
    #pragma unroll
    for (int c = 0; c < NCH; ++c) s += partial[c * NPIX * NPIX + p];
    // (1000*((fbp-0.0192)/0.0192)+1024)/4096 = fbp*(1000/0.0192/4096) + 24/4096
    out[p] = fmaf(s, (float)(1000.0 / 0.0192 / 4096.0), 0.005859375f);
}

extern "C" void kernel_launch(void* const* d_in, const int* in_sizes, int n_in,
                              void* d_out, int out_size, void* d_ws, size_t ws_size,
                              hipStream_t stream) {
    const float* x = (const float*)d_in[0];     // (1,1,1152,736) fp32 sinogram
    float* out = (float*)d_out;                 // (1,1,512,512) fp32

    char* ws = (char*)d_ws;
    double* filt_d = (double*)(ws + OFF_FILTD);
    float*  h      = (float*)(ws + OFF_H);
    float4* trig   = (float4*)(ws + OFF_TRIG);
    float*  fs     = (float*)(ws + OFF_FS);
    float*  part   = (float*)(ws + OFF_PART);

    filt_spec_kernel<<<NHALF, 256, 0, stream>>>(filt_d);
    h_kernel<<<PADN, 256, 0, stream>>>(filt_d, h, trig);
    conv_kernel<<<NAANG, 192, 0, stream>>>(x, h, fs);

    const size_t pbytes = (size_t)NPIX * NPIX * 4;
    if (ws_size >= OFF_PART + 8 * pbytes) {
        backproj_kernel<8><<<dim3(2, 128, 8), 256, 0, stream>>>(fs, trig, part);
        combine_kernel<8><<<NPIX * NPIX / 256, 256, 0, stream>>>(part, out);
    } else if (ws_size >= OFF_PART + 4 * pbytes) {
        backproj_kernel<4><<<dim3(2, 128, 4), 256, 0, stream>>>(fs, trig, part);
        combine_kernel<4><<<NPIX * NPIX / 256, 256, 0, stream>>>(part, out);
    } else if (ws_size >= OFF_PART + 2 * pbytes) {
        backproj_kernel<2><<<dim3(2, 128, 2), 256, 0, stream>>>(fs, trig, part);
        combine_kernel<2><<<NPIX * NPIX / 256, 256, 0, stream>>>(part, out);
    } else {
        backproj_kernel<1><<<dim3(2, 128, 1), 256, 0, stream>>>(fs, trig, part);
        combine_kernel<1><<<NPIX * NPIX / 256, 256, 0, stream>>>(part, out);
    }
}

// Round 7
// 264.251 us; speedup vs baseline: 1.0557x; 1.0032x over previous
//
#include <hip/hip_runtime.h>
#include <math.h>

#ifndef M_PI
#define M_PI 3.14159265358979323846
#endif

#define NAANG 1152
#define NDET  736
#define NPIX  512
#define PADN  2048
#define NHALF 1025   // PADN/2 + 1

// ---- workspace layout (byte offsets) ----
// float  cosT[2048]            @ 0        (8192 B)  cos(2*pi*r/2048)
// float  filt_f[1025]          @ 8192     (4100 B, pad 4224)
// float  h[2048]               @ 12416    (8192 B)  [pi/(2NA) scale folded]
// float4 trig[1152]            @ 20608    (18432 B) (cb, sb, K*cb, K*sb)
// float  filtered[1152*736]    @ 39040    (3391488 B)
// float  partial[NCH*512*512]  @ 3430528  (NCH MiB)
#define OFF_COST  0
#define OFF_FILTF 8192
#define OFF_H     12416
#define OFF_TRIG  20608
#define OFF_FS    39040
#define OFF_PART  3430528

typedef float f32x2 __attribute__((ext_vector_type(2)));

static __device__ __forceinline__ f32x2 load2(const float* p) {
    f32x2 r;
    __builtin_memcpy(&r, p, 8);
    return r;
}

// ---------------------------------------------------------------------------
// Kernel 0: cos table, small args only (fast path). cosT[r] = cos(2*pi*r/2048)
// ---------------------------------------------------------------------------
__global__ void costab_kernel(float* __restrict__ cosT) {
    int r = blockIdx.x * 256 + threadIdx.x;   // 0..2047
    cosT[r] = (float)cos(2.0 * M_PI * (double)r / (double)PADN);
}

// ---------------------------------------------------------------------------
// Kernel 1: FILT[m] via table: cos(2pi*m*(2j+1)/2048) = cosT[(m*(2j+1))&2047]
// ---------------------------------------------------------------------------
__global__ void filt_spec_kernel(const float* __restrict__ cosT,
                                 float* __restrict__ filt_f) {
    __shared__ float red[256];
    const int m = blockIdx.x;          // 0..1024
    const int t = threadIdx.x;
    float s = 0.f;
    for (int j = t; j < 1024; j += 256) {
        int n = (j < 512) ? (2 * j + 1) : (2047 - 2 * j);
        float fj = (float)(-1.0 / ((M_PI * n) * (M_PI * n)));
        s += fj * cosT[(m * (2 * j + 1)) & (PADN - 1)];
    }
    red[t] = s;
    __syncthreads();
    for (int w = 128; w > 0; w >>= 1) {
        if (t < w) red[t] += red[t + w];
        __syncthreads();
    }
    if (t == 0) {
        double four = 2.0 * (0.25 + (double)red[0]);
        if (m > 0) {
            double om = M_PI * (double)m / (double)PADN;
            four *= sin(om) / om;      // small arg, fast path
        }
        filt_f[m] = (float)four;
    }
}

// ---------------------------------------------------------------------------
// Kernel 2: h[k] = irfft(FILT,2048)[k] * pi/(2*NA) via table lookups;
// blocks k<1152 also fill the trig table on lane 0 (small-arg double trig).
// ---------------------------------------------------------------------------
__global__ void h_kernel(const float* __restrict__ cosT,
                         const float* __restrict__ filt_f,
                         float* __restrict__ h, float4* __restrict__ trig) {
    __shared__ float red[256];
    const int k = blockIdx.x;          // 0..2047
    const int t = threadIdx.x;
    if (t == 0 && k < NAANG) {
        double ang = 2.0 * M_PI * (double)k / (double)NAANG + M_PI / 2.0;
        double c = cos(ang), s = sin(ang);
        double K = 1085.6 / 1.2858;    // DSD/DU (vox scaling cancels)
        trig[k] = make_float4((float)c, (float)s, (float)(K * c), (float)(K * s));
    }
    float s = 0.f;
    for (int m = t; m <= 1024; m += 256) {
        float F = filt_f[m];
        float c;
        if (m == 0) c = 1.f;
        else if (m == 1024) c = (k & 1) ? -1.f : 1.f;
        else c = 2.f * cosT[(m * k) & (PADN - 1)];
        s += F * c;
    }
    red[t] = s;
    __syncthreads();
    for (int w = 128; w > 0; w >>= 1) {
        if (t < w) red[t] += red[t + w];
        __syncthreads();
    }
    if (t == 0)
        h[k] = (float)((double)red[0] / (double)PADN * (M_PI / (2.0 * (double)NAANG)));
}

// ---------------------------------------------------------------------------
// Kernel 3: circular convolution, aligned-b128 form (unchanged, passing).
// ---------------------------------------------------------------------------
__global__ void conv_kernel(const float* __restrict__ x,
                            const float* __restrict__ h,
                            float* __restrict__ fs) {
    __shared__ float sh2[2816];        // h duplicated: sh2[i] = h[i & 2047]
    __shared__ float srow[NDET];
    const int row = blockIdx.x;
    const int t = threadIdx.x;
    const float4* h4 = (const float4*)h;
    for (int i = t; i < 704; i += 192) ((float4*)sh2)[i] = h4[i & 511];
    const float4* x4 = (const float4*)(x + row * NDET);
    for (int i = t; i < NDET / 4; i += 192) ((float4*)srow)[i] = x4[i];
    __syncthreads();

    const int t4 = 4 * t;
    float o0 = 0.f, o1 = 0.f, o2 = 0.f, o3 = 0.f;
    #pragma unroll 2
    for (int j = 0; j < NDET; j += 4) {
        float4 r4 = *(const float4*)&srow[j];
        const int A = t4 + PADN - j;
        float4 hlo = *(const float4*)&sh2[A - 4];
        float4 hhi = *(const float4*)&sh2[A];
        o0 = fmaf(r4.x, hhi.x, o0); o0 = fmaf(r4.y, hlo.w, o0);
        o0 = fmaf(r4.z, hlo.z, o0); o0 = fmaf(r4.w, hlo.y, o0);
        o1 = fmaf(r4.x, hhi.y, o1); o1 = fmaf(r4.y, hhi.x, o1);
        o1 = fmaf(r4.z, hlo.w, o1); o1 = fmaf(r4.w, hlo.z, o1);
        o2 = fmaf(r4.x, hhi.z, o2); o2 = fmaf(r4.y, hhi.y, o2);
        o2 = fmaf(r4.z, hhi.x, o2); o2 = fmaf(r4.w, hlo.w, o2);
        o3 = fmaf(r4.x, hhi.w, o3); o3 = fmaf(r4.y, hhi.z, o3);
        o3 = fmaf(r4.z, hhi.y, o3); o3 = fmaf(r4.w, hhi.x, o3);
    }
    if (t < NDET / 4)
        *(float4*)&fs[row * NDET + t4] = make_float4(o0, o1, o2, o3);
}

// ---------------------------------------------------------------------------
// Kernel 4: fan-beam backprojection — manual 2-deep software pipeline.
// Stage GEO(a): geometry + issue 4 gathers (ping-pong A/B register sets);
// CONSUME(a) runs while GEO(a+1)'s loads are in flight -> waits become
// vmcnt(4)-class, not vmcnt(0). Trig read with wave-uniform index from
// global -> s_load_dwordx4 through the scalar pipe; no LDS, no barriers.
// 4 pixels/thread (adjacent y): den_k = den0 - k*sb, kpe_k = kpe0 + k*Kcb.
// grid (2, 128, NCH); NCH=8 -> 2048 blocks = 8/CU * 4 waves = 32 waves/CU.
// ---------------------------------------------------------------------------
#define GEO(AA, G0,G1,G2,G3, FR0,FR1,FR2,FR3, W0,W1,W2,W3)               \
  {                                                                      \
    float4 q = trig[abase + (AA)];   /* uniform -> scalar load */        \
    float den0 = fmaf(-xs, q.x, fmaf(-ys0, q.y, Dg));                    \
    float kpe0 = fmaf(ys0, q.z, -(xs * q.w));                            \
    float sb2 = q.y + q.y, kc2 = q.z + q.z;                              \
    float den1 = den0 - q.y, den2 = den0 - sb2, den3 = den2 - q.y;       \
    float kpe1 = kpe0 + q.z, kpe2 = kpe0 + kc2, kpe3 = kpe2 + q.z;       \
    float r0 = __builtin_amdgcn_rcpf(den0);                              \
    float r1 = __builtin_amdgcn_rcpf(den1);                              \
    float r2 = __builtin_amdgcn_rcpf(den2);                              \
    float r3 = __builtin_amdgcn_rcpf(den3);                              \
    float iu0 = fmaf(kpe0, r0, 367.5f);                                  \
    float iu1 = fmaf(kpe1, r1, 367.5f);                                  \
    float iu2 = fmaf(kpe2, r2, 367.5f);                                  \
    float iu3 = fmaf(kpe3, r3, 367.5f);                                  \
    float f0 = floorf(iu0), f1 = floorf(iu1);                            \
    float f2 = floorf(iu2), f3 = floorf(iu3);                            \
    int i0 = (int)f0, i1 = (int)f1, i2 = (int)f2, i3 = (int)f3;          \
    int c0 = min(max(i0, 0), NDET - 2);                                  \
    int c1 = min(max(i1, 0), NDET - 2);                                  \
    int c2 = min(max(i2, 0), NDET - 2);                                  \
    int c3 = min(max(i3, 0), NDET - 2);                                  \
    const float* rp = fs + (size_t)(abase + (AA)) * NDET;                \
    G0 = load2(rp + c0); G1 = load2(rp + c1);                            \
    G2 = load2(rp + c2); G3 = load2(rp + c3);                            \
    FR0 = iu0 - f0; FR1 = iu1 - f1; FR2 = iu2 - f2; FR3 = iu3 - f3;      \
    float d0 = Dg * r0, d1 = Dg * r1, d2 = Dg * r2, d3 = Dg * r3;        \
    W0 = ((unsigned)i0 < (unsigned)(NDET - 1)) ? d0 * d0 : 0.f;          \
    W1 = ((unsigned)i1 < (unsigned)(NDET - 1)) ? d1 * d1 : 0.f;          \
    W2 = ((unsigned)i2 < (unsigned)(NDET - 1)) ? d2 * d2 : 0.f;          \
    W3 = ((unsigned)i3 < (unsigned)(NDET - 1)) ? d3 * d3 : 0.f;          \
  }

#define CONSUME(G0,G1,G2,G3, FR0,FR1,FR2,FR3, W0,W1,W2,W3)               \
  {                                                                      \
    float v0 = fmaf(FR0, G0.y - G0.x, G0.x);                             \
    float v1 = fmaf(FR1, G1.y - G1.x, G1.x);                             \
    float v2 = fmaf(FR2, G2.y - G2.x, G2.x);                             \
    float v3 = fmaf(FR3, G3.y - G3.x, G3.x);                             \
    acc0 = fmaf(W0, v0, acc0); acc1 = fmaf(W1, v1, acc1);                \
    acc2 = fmaf(W2, v2, acc2); acc3 = fmaf(W3, v3, acc3);                \
  }

template<int NCH>
__global__ __launch_bounds__(256, 8)
void backproj_kernel(const float* __restrict__ fs,
                     const float4* __restrict__ trig,
                     float* __restrict__ partial) {
    constexpr int ACL = NAANG / NCH;   // 144 for NCH=8 (even for all NCH used)
    const int t = threadIdx.x;
    const int abase = blockIdx.z * ACL;
    const int ix = blockIdx.x * 256 + t;
    const int iy = blockIdx.y * 4;
    const float xs  = (float)ix - 255.5f;
    const float ys0 = (float)iy - 255.5f;
    const float Dg = 850.0f;           // 595/0.7 exactly

    float acc0 = 0.f, acc1 = 0.f, acc2 = 0.f, acc3 = 0.f;
    f32x2 Ag0, Ag1, Ag2, Ag3, Bg0, Bg1, Bg2, Bg3;
    float Af0, Af1, Af2, Af3, Aw0, Aw1, Aw2, Aw3;
    float Bf0, Bf1, Bf2, Bf3, Bw0, Bw1, Bw2, Bw3;

    GEO(0, Ag0,Ag1,Ag2,Ag3, Af0,Af1,Af2,Af3, Aw0,Aw1,Aw2,Aw3);
    int a = 0;
    for (; a + 2 < ACL; a += 2) {
        GEO(a + 1, Bg0,Bg1,Bg2,Bg3, Bf0,Bf1,Bf2,Bf3, Bw0,Bw1,Bw2,Bw3);
        CONSUME(Ag0,Ag1,Ag2,Ag3, Af0,Af1,Af2,Af3, Aw0,Aw1,Aw2,Aw3);
        GEO(a + 2, Ag0,Ag1,Ag2,Ag3, Af0,Af1,Af2,Af3, Aw0,Aw1,Aw2,Aw3);
        CONSUME(Bg0,Bg1,Bg2,Bg3, Bf0,Bf1,Bf2,Bf3, Bw0,Bw1,Bw2,Bw3);
    }
    GEO(ACL - 1, Bg0,Bg1,Bg2,Bg3, Bf0,Bf1,Bf2,Bf3, Bw0,Bw1,Bw2,Bw3);
    CONSUME(Ag0,Ag1,Ag2,Ag3, Af0,Af1,Af2,Af3, Aw0,Aw1,Aw2,Aw3);
    CONSUME(Bg0,Bg1,Bg2,Bg3, Bf0,Bf1,Bf2,Bf3, Bw0,Bw1,Bw2,Bw3);

    float* outp = partial + ((size_t)blockIdx.z * NPIX + iy) * NPIX + ix;
    outp[0 * NPIX] = acc0;
    outp[1 * NPIX] = acc1;
    outp[2 * NPIX] = acc2;
    outp[3 * NPIX] = acc3;
}

// ---------------------------------------------------------------------------
// Kernel 5: sum partials + HU window.
// ---------------------------------------------------------------------------
template<int NCH>
__global__ void combine_kernel(const float* __restrict__ partial,
                               float* __restrict__ out) {
    int p = blockIdx.x * 256 + threadIdx.x;
    float s = 0.f;
    #pragma unroll
    for (int c = 0; c < NCH; ++c) s += partial[c * NPIX * NPIX + p];
    // (1000*((fbp-0.0192)/0.0192)+1024)/4096 = fbp*(1000/0.0192/4096) + 24/4096
    out[p] = fmaf(s, (float)(1000.0 / 0.0192 / 4096.0), 0.005859375f);
}

extern "C" void kernel_launch(void* const* d_in, const int* in_sizes, int n_in,
                              void* d_out, int out_size, void* d_ws, size_t ws_size,
                              hipStream_t stream) {
    const float* x = (const float*)d_in[0];     // (1,1,1152,736) fp32 sinogram
    float* out = (float*)d_out;                 // (1,1,512,512) fp32

    char* ws = (char*)d_ws;
    float*  cosT   = (float*)(ws + OFF_COST);
    float*  filt_f = (float*)(ws + OFF_FILTF);
    float*  h      = (float*)(ws + OFF_H);
    float4* trig   = (float4*)(ws + OFF_TRIG);
    float*  fs     = (float*)(ws + OFF_FS);
    float*  part   = (float*)(ws + OFF_PART);

    costab_kernel<<<PADN / 256, 256, 0, stream>>>(cosT);
    filt_spec_kernel<<<NHALF, 256, 0, stream>>>(cosT, filt_f);
    h_kernel<<<PADN, 256, 0, stream>>>(cosT, filt_f, h, trig);
    conv_kernel<<<NAANG, 192, 0, stream>>>(x, h, fs);

    const size_t pbytes = (size_t)NPIX * NPIX * 4;
    if (ws_size >= OFF_PART + 8 * pbytes) {
        backproj_kernel<8><<<dim3(2, 128, 8), 256, 0, stream>>>(fs, trig, part);
        combine_kernel<8><<<NPIX * NPIX / 256, 256, 0, stream>>>(part, out);
    } else if (ws_size >= OFF_PART + 4 * pbytes) {
        backproj_kernel<4><<<dim3(2, 128, 4), 256, 0, stream>>>(fs, trig, part);
        combine_kernel<4><<<NPIX * NPIX / 256, 256, 0, stream>>>(part, out);
    } else if (ws_size >= OFF_PART + 2 * pbytes) {
        backproj_kernel<2><<<dim3(2, 128, 2), 256, 0, stream>>>(fs, trig, part);
        combine_kernel<2><<<NPIX * NPIX / 256, 256, 0, stream>>>(part, out);
    } else {
        backproj_kernel<1><<<dim3(2, 128, 1), 256, 0, stream>>>(fs, trig, part);
        combine_kernel<1><<<NPIX * NPIX / 256, 256, 0, stream>>>(part, out);
    }
}